// Round 4
// baseline (1678.522 us; speedup 1.0000x reference)
//
#include <hip/hip_runtime.h>
#include <hip/hip_bf16.h>

#define NODE_F 74
#define HID 128
#define DIM 256

typedef __hip_bfloat16 bf16;
typedef unsigned int u32;
typedef unsigned short u16;

__device__ __forceinline__ float rdl(float v, int l){
  return __int_as_float(__builtin_amdgcn_readlane(__float_as_int(v), l));
}
// unpack two bf16 (packed low=first, high=second) to two floats
__device__ __forceinline__ float2 bfpair(u32 u){
  float2 r;
  r.x = __uint_as_float(u << 16);
  r.y = __uint_as_float(u & 0xffff0000u);
  return r;
}
__device__ __forceinline__ u32 packbf(float a, float b){
  u32 lo = (u32)__bfloat16_as_ushort(__float2bfloat16(a));
  u32 hi = (u32)__bfloat16_as_ushort(__float2bfloat16(b));
  return lo | (hi << 16);
}
// stage fp32 global weights into LDS as packed bf16 pairs
__device__ __forceinline__ void stage_wf(const float* __restrict__ g, u32* __restrict__ s,
                                         int count_u32, int tid){
  for (int i = tid; i < count_u32; i += 256){
    s[i] = packbf(g[2*i], g[2*i+1]);
  }
}

// ---------------- degrees ----------------
__global__ void k_deg(const int* __restrict__ src, const int* __restrict__ dst,
                      float* __restrict__ outdeg_f, int* __restrict__ indeg, int E_){
  int e = blockIdx.x*256 + threadIdx.x;
  if (e < E_){
    atomicAdd(&outdeg_f[src[e]], 1.0f);
    atomicAdd(&indeg[dst[e]], 1);
  }
}

__global__ void k_norm(float* __restrict__ norm_s, const int* __restrict__ indeg,
                       float* __restrict__ norm_d, int n){
  int i = blockIdx.x*256 + threadIdx.x;
  if (i < n){
    norm_s[i] = rsqrtf(fmaxf(norm_s[i], 1.0f));
    norm_d[i] = rsqrtf(fmaxf((float)indeg[i], 1.0f));
  }
}

// ---------------- CSR build ----------------
__global__ __launch_bounds__(1024) void k_scan(int* __restrict__ indeg,
                                               int* __restrict__ row_ptr, int n){
  __shared__ int part[1024];
  const int T = 1024;
  const int tid = threadIdx.x;
  const int chunk = (n + T - 1) / T;
  const int lo = tid*chunk;
  const int hi = (lo + chunk < n) ? lo + chunk : n;
  int s = 0;
  for (int i = lo; i < hi; ++i) s += indeg[i];
  part[tid] = s;
  __syncthreads();
  for (int off = 1; off < T; off <<= 1){
    int v = (tid >= off) ? part[tid-off] : 0;
    __syncthreads();
    part[tid] += v;
    __syncthreads();
  }
  int run = (tid == 0) ? 0 : part[tid-1];
  for (int i = lo; i < hi; ++i){
    int c = indeg[i];
    row_ptr[i] = run;
    run += c;
    indeg[i] = 0;            // becomes cursor for k_fill
  }
  if (tid == T-1) row_ptr[n] = run;
}

__global__ void k_fill(const int* __restrict__ src, const int* __restrict__ dst,
                       const int* __restrict__ row_ptr, int* __restrict__ cursor,
                       int* __restrict__ col, int E_){
  int e = blockIdx.x*256 + threadIdx.x;
  if (e < E_){
    int d = dst[e];
    int pos = row_ptr[d] + atomicAdd(&cursor[d], 1);
    col[pos] = src[e];
  }
}

// ---------------- layer 1: h1 = relu((agg*nd)@W1+b1)+relu(x0@Wr1+br1), packed bf16 out
__global__ __launch_bounds__(256) void k_layer1(
    const float* __restrict__ x0, const int* __restrict__ row_ptr,
    const int* __restrict__ col, const float* __restrict__ norm_s,
    const float* __restrict__ norm_d,
    const float* __restrict__ W1, const float* __restrict__ b1,
    const float* __restrict__ Wr1, const float* __restrict__ br1,
    u32* __restrict__ h1u, int n){
  __shared__ u32 sW[NODE_F*HID/2];    // 18944 B (bf16 pairs)
  __shared__ u32 sWr[NODE_F*HID/2];
  stage_wf(W1,  sW,  NODE_F*HID/2, threadIdx.x);
  stage_wf(Wr1, sWr, NODE_F*HID/2, threadIdx.x);
  __syncthreads();
  const int lane = threadIdx.x & 63;
  const int wid  = (blockIdx.x*blockDim.x + threadIdx.x) >> 6;
  const int nw   = (gridDim.x*blockDim.x) >> 6;
  const int c = lane*2;
  const float bg0 = b1[c],  bg1 = b1[c+1];
  const float bb0 = br1[c], bb1 = br1[c+1];
  for (int row = wid; row < n; row += nw){
    // lane holds K-features {lane, 64+lane} of this row's A-vectors
    float rx0 = x0[(size_t)row*NODE_F + lane];
    float rx1 = (lane < NODE_F-64) ? x0[(size_t)row*NODE_F + 64 + lane] : 0.0f;
    float ga0 = 0.f, ga1 = 0.f;
    const int p0 = row_ptr[row], p1 = row_ptr[row+1];
    for (int p = p0; p < p1; ++p){
      const int s = col[p];
      const float ns = norm_s[s];
      ga0 = fmaf(x0[(size_t)s*NODE_F + lane], ns, ga0);
      if (lane < NODE_F-64) ga1 = fmaf(x0[(size_t)s*NODE_F + 64 + lane], ns, ga1);
    }
    const float nd = norm_d[row];
    ga0 *= nd; ga1 *= nd;
    float ag0=0.f, ag1=0.f, ar0=0.f, ar1=0.f;
    #pragma unroll
    for (int k = 0; k < 64; ++k){
      const float a = rdl(ga0, k);
      const float x = rdl(rx0, k);
      const float2 w  = bfpair(sW[k*64 + lane]);
      const float2 wr = bfpair(sWr[k*64 + lane]);
      ag0 = fmaf(a, w.x, ag0);  ag1 = fmaf(a, w.y, ag1);
      ar0 = fmaf(x, wr.x, ar0); ar1 = fmaf(x, wr.y, ar1);
    }
    #pragma unroll
    for (int k = 64; k < NODE_F; ++k){
      const float a = rdl(ga1, k-64);
      const float x = rdl(rx1, k-64);
      const float2 w  = bfpair(sW[k*64 + lane]);
      const float2 wr = bfpair(sWr[k*64 + lane]);
      ag0 = fmaf(a, w.x, ag0);  ag1 = fmaf(a, w.y, ag1);
      ar0 = fmaf(x, wr.x, ar0); ar1 = fmaf(x, wr.y, ar1);
    }
    const float o0 = fmaxf(ag0+bg0, 0.f) + fmaxf(ar0+bb0, 0.f);
    const float o1 = fmaxf(ag1+bg1, 0.f) + fmaxf(ar1+bb1, 0.f);
    h1u[(size_t)row*(HID/2) + lane] = packbf(o0, o1);
  }
}

// ---------------- layer 2 + readout (h1 packed bf16 pairs; lane holds cols {2L,2L+1})
__global__ __launch_bounds__(256) void k_layer2(
    const u32* __restrict__ h1u, const int* __restrict__ row_ptr,
    const int* __restrict__ col, const float* __restrict__ norm_s,
    const float* __restrict__ norm_d,
    const float* __restrict__ W2, const float* __restrict__ b2,
    const float* __restrict__ Wr2, const float* __restrict__ br2,
    const float* __restrict__ w_atom, const float* __restrict__ b_atom,
    const int* __restrict__ gid,
    float* __restrict__ hsum, u32* __restrict__ hmax, int n){
  __shared__ u32 sW[HID*HID/2];     // 32 KB (bf16 pairs)
  __shared__ u32 sWr[HID*HID/2];    // 32 KB
  stage_wf(W2,  sW,  HID*HID/2, threadIdx.x);
  stage_wf(Wr2, sWr, HID*HID/2, threadIdx.x);
  __syncthreads();
  const int lane = threadIdx.x & 63;
  const int wid  = (blockIdx.x*blockDim.x + threadIdx.x) >> 6;
  const int nw   = (gridDim.x*blockDim.x) >> 6;
  const int c = lane*2;
  const float bg0 = b2[c],  bg1 = b2[c+1];
  const float bb0 = br2[c], bb1 = br2[c+1];
  const float wa0 = w_atom[c], wa1 = w_atom[c+1];
  const float ba  = b_atom[0];
  for (int row = wid; row < n; row += nw){
    const float2 rh = bfpair(h1u[(size_t)row*(HID/2) + lane]);   // feats c, c+1
    float ga0 = 0.f, ga1 = 0.f;
    const int p0 = row_ptr[row], p1 = row_ptr[row+1];
    for (int p = p0; p < p1; ++p){
      const int s = col[p];
      const float ns = norm_s[s];
      const float2 v = bfpair(h1u[(size_t)s*(HID/2) + lane]);
      ga0 = fmaf(v.x, ns, ga0);
      ga1 = fmaf(v.y, ns, ga1);
    }
    const float nd = norm_d[row];
    ga0 *= nd; ga1 *= nd;     // feats c, c+1 of normalized agg
    float ag0=0.f, ag1=0.f, ar0=0.f, ar1=0.f;
    // K-loop: feature 2j lives in lane j comp .x, feature 2j+1 in lane j comp .y
    #pragma unroll
    for (int j = 0; j < 64; ++j){
      const float ae = rdl(ga0, j);          // feature 2j   (agg)
      const float ao = rdl(ga1, j);          // feature 2j+1 (agg)
      const float xe = rdl(rh.x, j);         // feature 2j   (residual)
      const float xo = rdl(rh.y, j);         // feature 2j+1 (residual)
      const float2 we  = bfpair(sW[(2*j  )*64 + lane]);
      const float2 wo  = bfpair(sW[(2*j+1)*64 + lane]);
      const float2 wre = bfpair(sWr[(2*j  )*64 + lane]);
      const float2 wro = bfpair(sWr[(2*j+1)*64 + lane]);
      ag0 = fmaf(ae, we.x, fmaf(ao, wo.x, ag0));
      ag1 = fmaf(ae, we.y, fmaf(ao, wo.y, ag1));
      ar0 = fmaf(xe, wre.x, fmaf(xo, wro.x, ar0));
      ar1 = fmaf(xe, wre.y, fmaf(xo, wro.y, ar1));
    }
    const float h0  = fmaxf(ag0+bg0, 0.f) + fmaxf(ar0+bb0, 0.f);
    const float h1v = fmaxf(ag1+bg1, 0.f) + fmaxf(ar1+bb1, 0.f);
    float t = fmaf(h0, wa0, h1v*wa1);
    #pragma unroll
    for (int off = 32; off; off >>= 1) t += __shfl_xor(t, off);
    const float aw = 1.0f/(1.0f + __expf(-(t + ba)));
    const int g = gid[row];
    atomicAdd(&hsum[(size_t)g*HID + c],   h0*aw);
    atomicAdd(&hsum[(size_t)g*HID + c+1], h1v*aw);
    atomicMax(&hmax[(size_t)g*HID + c],   __float_as_uint(h0));   // h>=0
    atomicMax(&hmax[(size_t)g*HID + c+1], __float_as_uint(h1v));
  }
}

// ---------------- MLP layer 1: hid = relu(concat(hsum,hmax) @ Wp1 + bp1) ----------------
// Weights read fp32 from global (L2-hot): no rounding in the high-magnitude tail.
__global__ __launch_bounds__(256) void k_mlp1(
    const float* __restrict__ hsum, const float* __restrict__ hmaxf,
    const float* __restrict__ Wp1, const float* __restrict__ bp1,
    float* __restrict__ hid, int G_){
  const int lane = threadIdx.x & 63;
  const int row = blockIdx.x*4 + (threadIdx.x >> 6);
  if (row >= G_) return;
  const int c = lane*2;
  float ra0 = hsum[(size_t)row*HID + lane];
  float ra1 = hsum[(size_t)row*HID + 64 + lane];
  float ra2 = hmaxf[(size_t)row*HID + lane];
  float ra3 = hmaxf[(size_t)row*HID + 64 + lane];
  float a0 = 0.f, a1 = 0.f;
  #pragma unroll 8
  for (int k = 0; k < 64; ++k){
    const float v0 = rdl(ra0,k), v1 = rdl(ra1,k), v2 = rdl(ra2,k), v3 = rdl(ra3,k);
    const float2 w0 = *(const float2*)&Wp1[(size_t)(k      )*HID + c];
    const float2 w1 = *(const float2*)&Wp1[(size_t)(k +  64)*HID + c];
    const float2 w2 = *(const float2*)&Wp1[(size_t)(k + 128)*HID + c];
    const float2 w3 = *(const float2*)&Wp1[(size_t)(k + 192)*HID + c];
    a0 = fmaf(v0,w0.x, fmaf(v1,w1.x, fmaf(v2,w2.x, fmaf(v3,w3.x, a0))));
    a1 = fmaf(v0,w0.y, fmaf(v1,w1.y, fmaf(v2,w2.y, fmaf(v3,w3.y, a1))));
  }
  hid[(size_t)row*HID + c]   = fmaxf(a0 + bp1[c],   0.f);
  hid[(size_t)row*HID + c+1] = fmaxf(a1 + bp1[c+1], 0.f);
}

// ---------------- MLP layer 2 + zero-row insertion ----------------
__global__ __launch_bounds__(256) void k_mlp2(
    const float* __restrict__ hid, const float* __restrict__ Wp2,
    const float* __restrict__ bp2, const int* __restrict__ idxw, int K_,
    float* __restrict__ out, int G_){
  const int lane = threadIdx.x & 63;
  const int row = blockIdx.x*4 + (threadIdx.x >> 6);
  if (row >= G_) return;
  const int c = lane*4;
  float ra0 = hid[(size_t)row*HID + lane];
  float ra1 = hid[(size_t)row*HID + 64 + lane];
  float acc0=0.f, acc1=0.f, acc2=0.f, acc3=0.f;
  #pragma unroll 8
  for (int k = 0; k < 64; ++k){
    const float a = rdl(ra0, k);
    const float4 w = *(const float4*)&Wp2[(size_t)k*DIM + c];
    acc0 = fmaf(a,w.x,acc0); acc1 = fmaf(a,w.y,acc1);
    acc2 = fmaf(a,w.z,acc2); acc3 = fmaf(a,w.w,acc3);
  }
  #pragma unroll 8
  for (int k = 64; k < 128; ++k){
    const float a = rdl(ra1, k-64);
    const float4 w = *(const float4*)&Wp2[(size_t)k*DIM + c];
    acc0 = fmaf(a,w.x,acc0); acc1 = fmaf(a,w.y,acc1);
    acc2 = fmaf(a,w.z,acc2); acc3 = fmaf(a,w.w,acc3);
  }
  int orow = row;
  for (int j = 0; j < K_; ++j){ if (idxw[j] <= orow) orow++; }
  float* po = out + (size_t)orow*DIM + c;
  po[0] = acc0 + bp2[c];
  po[1] = acc1 + bp2[c+1];
  po[2] = acc2 + bp2[c+2];
  po[3] = acc3 + bp2[c+3];
}

extern "C" void kernel_launch(void* const* d_in, const int* in_sizes, int n_in,
                              void* d_out, int out_size, void* d_ws, size_t ws_size,
                              hipStream_t stream){
  (void)n_in; (void)ws_size;
  const float* x0     = (const float*)d_in[0];
  // d_in[1] = edge_feats (unused by the reference GCN)
  const float* W1     = (const float*)d_in[2];
  const float* b1     = (const float*)d_in[3];
  const float* Wr1    = (const float*)d_in[4];
  const float* br1    = (const float*)d_in[5];
  const float* W2     = (const float*)d_in[6];
  const float* b2     = (const float*)d_in[7];
  const float* Wr2    = (const float*)d_in[8];
  const float* br2    = (const float*)d_in[9];
  const float* w_atom = (const float*)d_in[10];
  const float* b_atom = (const float*)d_in[11];
  const float* Wp1    = (const float*)d_in[12];
  const float* bp1    = (const float*)d_in[13];
  const float* Wp2    = (const float*)d_in[14];
  const float* bp2    = (const float*)d_in[15];
  const int* src  = (const int*)d_in[16];
  const int* dst  = (const int*)d_in[17];
  const int* gid  = (const int*)d_in[18];
  const int* idxw = (const int*)d_in[19];

  const int N_ = in_sizes[0] / NODE_F;
  const int E_ = in_sizes[16];
  const int K_ = in_sizes[19];
  const int G_ = out_size / DIM - K_;

  // workspace (~33 MB):
  //   [h1u N*64 u32][norm_s N][norm_d N][hsum G*128][hmax G*128][hid G*128]
  //   [indeg/cursor N][row_ptr N+1][col E]
  u32*   h1u     = (u32*)d_ws;
  float* norm_s  = (float*)(h1u + (size_t)N_*(HID/2));
  float* norm_d  = norm_s + N_;
  float* hsum    = norm_d + N_;
  float* hmax    = hsum + (size_t)G_*HID;
  float* hid     = hmax + (size_t)G_*HID;
  int*   indeg   = (int*)(hid + (size_t)G_*HID);
  int*   row_ptr = indeg + N_;
  int*   col     = row_ptr + N_ + 1;

  hipMemsetAsync(norm_s, 0, ((size_t)2*N_ + (size_t)2*G_*HID)*sizeof(float), stream);
  hipMemsetAsync(indeg, 0, (size_t)N_*sizeof(int), stream);
  hipMemsetAsync(d_out, 0, (size_t)out_size*sizeof(float), stream);

  k_deg <<<(E_+255)/256, 256, 0, stream>>>(src, dst, norm_s, indeg, E_);
  k_norm<<<(N_+255)/256, 256, 0, stream>>>(norm_s, indeg, norm_d, N_);
  k_scan<<<1, 1024, 0, stream>>>(indeg, row_ptr, N_);
  k_fill<<<(E_+255)/256, 256, 0, stream>>>(src, dst, row_ptr, indeg, col, E_);

  k_layer1<<<2048, 256, 0, stream>>>(x0, row_ptr, col, norm_s, norm_d,
                                     W1, b1, Wr1, br1, h1u, N_);
  k_layer2<<<2048, 256, 0, stream>>>(h1u, row_ptr, col, norm_s, norm_d,
                                     W2, b2, Wr2, br2, w_atom, b_atom, gid,
                                     hsum, (u32*)hmax, N_);

  k_mlp1<<<(G_+3)/4, 256, 0, stream>>>(hsum, hmax, Wp1, bp1, hid, G_);
  k_mlp2<<<(G_+3)/4, 256, 0, stream>>>(hid, Wp2, bp2, idxw, K_, (float*)d_out, G_);
}

// Round 5
// 1016.441 us; speedup vs baseline: 1.6514x; 1.6514x over previous
//
#include <hip/hip_runtime.h>
#include <hip/hip_bf16.h>

#define NODE_F 74
#define HID 128
#define DIM 256

typedef __hip_bfloat16 bf16;
typedef unsigned int u32;

__device__ __forceinline__ float rdl(float v, int l){
  return __int_as_float(__builtin_amdgcn_readlane(__float_as_int(v), l));
}
__device__ __forceinline__ float2 bfpair(u32 u){
  float2 r;
  r.x = __uint_as_float(u << 16);
  r.y = __uint_as_float(u & 0xffff0000u);
  return r;
}
__device__ __forceinline__ u32 packbf(float a, float b){
  u32 lo = (u32)__bfloat16_as_ushort(__float2bfloat16(a));
  u32 hi = (u32)__bfloat16_as_ushort(__float2bfloat16(b));
  return lo | (hi << 16);
}

// ---------------- degrees ----------------
__global__ void k_deg(const int* __restrict__ src, const int* __restrict__ dst,
                      float* __restrict__ outdeg_f, int* __restrict__ indeg, int E_){
  int e = blockIdx.x*256 + threadIdx.x;
  if (e < E_){
    atomicAdd(&outdeg_f[src[e]], 1.0f);
    atomicAdd(&indeg[dst[e]], 1);
  }
}

__global__ void k_norm(float* __restrict__ norm_s, const int* __restrict__ indeg,
                       float* __restrict__ norm_d, int n){
  int i = blockIdx.x*256 + threadIdx.x;
  if (i < n){
    norm_s[i] = rsqrtf(fmaxf(norm_s[i], 1.0f));
    norm_d[i] = rsqrtf(fmaxf((float)indeg[i], 1.0f));
  }
}

// ---------------- CSR build ----------------
__global__ __launch_bounds__(1024) void k_scan(int* __restrict__ indeg,
                                               int* __restrict__ row_ptr, int n){
  __shared__ int part[1024];
  const int T = 1024;
  const int tid = threadIdx.x;
  const int chunk = (n + T - 1) / T;
  const int lo = tid*chunk;
  const int hi = (lo + chunk < n) ? lo + chunk : n;
  int s = 0;
  for (int i = lo; i < hi; ++i) s += indeg[i];
  part[tid] = s;
  __syncthreads();
  for (int off = 1; off < T; off <<= 1){
    int v = (tid >= off) ? part[tid-off] : 0;
    __syncthreads();
    part[tid] += v;
    __syncthreads();
  }
  int run = (tid == 0) ? 0 : part[tid-1];
  for (int i = lo; i < hi; ++i){
    int c = indeg[i];
    row_ptr[i] = run;
    run += c;
    indeg[i] = 0;            // becomes cursor for k_fill
  }
  if (tid == T-1) row_ptr[n] = run;
}

__global__ void k_fill(const int* __restrict__ src, const int* __restrict__ dst,
                       const int* __restrict__ row_ptr, int* __restrict__ cursor,
                       int* __restrict__ col, int E_){
  int e = blockIdx.x*256 + threadIdx.x;
  if (e < E_){
    int d = dst[e];
    int pos = row_ptr[d] + atomicAdd(&cursor[d], 1);
    col[pos] = src[e];
  }
}

// ---------------- layer 1: h1 = relu((agg*nd)@W1+b1)+relu(x0@Wr1+br1), packed bf16 out
// LDS: one interleaved tile, entry (k,lane) = {W1[k][2L..2L+1], Wr1[k][2L..2L+1]} as uint2
__global__ __launch_bounds__(256) void k_layer1(
    const float* __restrict__ x0, const int* __restrict__ row_ptr,
    const int* __restrict__ col, const float* __restrict__ norm_s,
    const float* __restrict__ norm_d,
    const float* __restrict__ W1, const float* __restrict__ b1,
    const float* __restrict__ Wr1, const float* __restrict__ br1,
    u32* __restrict__ h1u, int n){
  __shared__ uint2 sC[NODE_F*64];    // 37888 B
  for (int i = threadIdx.x; i < NODE_F*64; i += 256){
    const int k = i >> 6, l = i & 63, c0 = 2*l;
    uint2 v;
    v.x = packbf(W1 [(size_t)k*HID + c0], W1 [(size_t)k*HID + c0+1]);
    v.y = packbf(Wr1[(size_t)k*HID + c0], Wr1[(size_t)k*HID + c0+1]);
    sC[i] = v;
  }
  __syncthreads();
  const int lane = threadIdx.x & 63;
  const int wid  = (blockIdx.x*blockDim.x + threadIdx.x) >> 6;
  const int nw   = (gridDim.x*blockDim.x) >> 6;
  const int c = lane*2;
  const float bg0 = b1[c],  bg1 = b1[c+1];
  const float bb0 = br1[c], bb1 = br1[c+1];
  for (int row = wid; row < n; row += nw){
    // lane holds K-features {lane, 64+lane} of this row's A-vectors
    float rx0 = x0[(size_t)row*NODE_F + lane];
    float rx1 = (lane < NODE_F-64) ? x0[(size_t)row*NODE_F + 64 + lane] : 0.0f;
    float ga0 = 0.f, ga1 = 0.f;
    const int p0 = row_ptr[row], p1 = row_ptr[row+1];
    for (int p = p0; p < p1; ++p){
      const int s = col[p];
      const float ns = norm_s[s];
      ga0 = fmaf(x0[(size_t)s*NODE_F + lane], ns, ga0);
      if (lane < NODE_F-64) ga1 = fmaf(x0[(size_t)s*NODE_F + 64 + lane], ns, ga1);
    }
    const float nd = norm_d[row];
    ga0 *= nd; ga1 *= nd;
    float ag0=0.f, ag1=0.f, ar0=0.f, ar1=0.f;
    #pragma unroll 4
    for (int k = 0; k < 64; ++k){
      const float a = rdl(ga0, k);
      const float x = rdl(rx0, k);
      const uint2 wv = sC[k*64 + lane];
      const float2 w  = bfpair(wv.x);
      const float2 wr = bfpair(wv.y);
      ag0 = fmaf(a, w.x, ag0);  ag1 = fmaf(a, w.y, ag1);
      ar0 = fmaf(x, wr.x, ar0); ar1 = fmaf(x, wr.y, ar1);
    }
    #pragma unroll 2
    for (int k = 64; k < NODE_F; ++k){
      const float a = rdl(ga1, k-64);
      const float x = rdl(rx1, k-64);
      const uint2 wv = sC[k*64 + lane];
      const float2 w  = bfpair(wv.x);
      const float2 wr = bfpair(wv.y);
      ag0 = fmaf(a, w.x, ag0);  ag1 = fmaf(a, w.y, ag1);
      ar0 = fmaf(x, wr.x, ar0); ar1 = fmaf(x, wr.y, ar1);
    }
    const float o0 = fmaxf(ag0+bg0, 0.f) + fmaxf(ar0+bb0, 0.f);
    const float o1 = fmaxf(ag1+bg1, 0.f) + fmaxf(ar1+bb1, 0.f);
    h1u[(size_t)row*(HID/2) + lane] = packbf(o0, o1);
  }
}

// ---------------- layer 2 + readout (h1 packed bf16 pairs; lane holds cols {2L,2L+1})
// LDS: interleaved tile, entry (j,lane) = {W2[2j], W2[2j+1], Wr2[2j], Wr2[2j+1]}[2L..2L+1] as uint4
__global__ __launch_bounds__(256) void k_layer2(
    const u32* __restrict__ h1u, const int* __restrict__ row_ptr,
    const int* __restrict__ col, const float* __restrict__ norm_s,
    const float* __restrict__ norm_d,
    const float* __restrict__ W2, const float* __restrict__ b2,
    const float* __restrict__ Wr2, const float* __restrict__ br2,
    const float* __restrict__ w_atom, const float* __restrict__ b_atom,
    const int* __restrict__ gid,
    float* __restrict__ hsum, u32* __restrict__ hmax, int n){
  __shared__ uint4 sC[64*64];       // 64 KB
  for (int i = threadIdx.x; i < 64*64; i += 256){
    const int j = i >> 6, l = i & 63, c0 = 2*l;
    const int k0 = 2*j, k1 = 2*j+1;
    uint4 v;
    v.x = packbf(W2 [(size_t)k0*HID + c0], W2 [(size_t)k0*HID + c0+1]);
    v.y = packbf(W2 [(size_t)k1*HID + c0], W2 [(size_t)k1*HID + c0+1]);
    v.z = packbf(Wr2[(size_t)k0*HID + c0], Wr2[(size_t)k0*HID + c0+1]);
    v.w = packbf(Wr2[(size_t)k1*HID + c0], Wr2[(size_t)k1*HID + c0+1]);
    sC[i] = v;
  }
  __syncthreads();
  const int lane = threadIdx.x & 63;
  const int wid  = (blockIdx.x*blockDim.x + threadIdx.x) >> 6;
  const int nw   = (gridDim.x*blockDim.x) >> 6;
  const int c = lane*2;
  const float bg0 = b2[c],  bg1 = b2[c+1];
  const float bb0 = br2[c], bb1 = br2[c+1];
  const float wa0 = w_atom[c], wa1 = w_atom[c+1];
  const float ba  = b_atom[0];
  for (int row = wid; row < n; row += nw){
    const float2 rh = bfpair(h1u[(size_t)row*(HID/2) + lane]);   // feats c, c+1
    float ga0 = 0.f, ga1 = 0.f;
    const int p0 = row_ptr[row], p1 = row_ptr[row+1];
    for (int p = p0; p < p1; ++p){
      const int s = col[p];
      const float ns = norm_s[s];
      const float2 v = bfpair(h1u[(size_t)s*(HID/2) + lane]);
      ga0 = fmaf(v.x, ns, ga0);
      ga1 = fmaf(v.y, ns, ga1);
    }
    const float nd = norm_d[row];
    ga0 *= nd; ga1 *= nd;     // feats c, c+1 of normalized agg
    float ag0=0.f, ag1=0.f, ar0=0.f, ar1=0.f;
    // K-loop: feature 2j lives in lane j comp .x, feature 2j+1 in lane j comp .y
    #pragma unroll 4
    for (int j = 0; j < 64; ++j){
      const uint4 wv = sC[j*64 + lane];
      const float ae = rdl(ga0, j);          // feature 2j   (agg)
      const float ao = rdl(ga1, j);          // feature 2j+1 (agg)
      const float xe = rdl(rh.x, j);         // feature 2j   (residual)
      const float xo = rdl(rh.y, j);         // feature 2j+1 (residual)
      const float2 we  = bfpair(wv.x);
      const float2 wo  = bfpair(wv.y);
      const float2 wre = bfpair(wv.z);
      const float2 wro = bfpair(wv.w);
      ag0 = fmaf(ae, we.x, fmaf(ao, wo.x, ag0));
      ag1 = fmaf(ae, we.y, fmaf(ao, wo.y, ag1));
      ar0 = fmaf(xe, wre.x, fmaf(xo, wro.x, ar0));
      ar1 = fmaf(xe, wre.y, fmaf(xo, wro.y, ar1));
    }
    const float h0  = fmaxf(ag0+bg0, 0.f) + fmaxf(ar0+bb0, 0.f);
    const float h1v = fmaxf(ag1+bg1, 0.f) + fmaxf(ar1+bb1, 0.f);
    float t = fmaf(h0, wa0, h1v*wa1);
    #pragma unroll
    for (int off = 32; off; off >>= 1) t += __shfl_xor(t, off);
    const float aw = 1.0f/(1.0f + __expf(-(t + ba)));
    const int g = gid[row];
    atomicAdd(&hsum[(size_t)g*HID + c],   h0*aw);
    atomicAdd(&hsum[(size_t)g*HID + c+1], h1v*aw);
    atomicMax(&hmax[(size_t)g*HID + c],   __float_as_uint(h0));   // h>=0
    atomicMax(&hmax[(size_t)g*HID + c+1], __float_as_uint(h1v));
  }
}

// ---------------- MLP layer 1: hid = relu(concat(hsum,hmax) @ Wp1 + bp1) ----------------
__global__ __launch_bounds__(256) void k_mlp1(
    const float* __restrict__ hsum, const float* __restrict__ hmaxf,
    const float* __restrict__ Wp1, const float* __restrict__ bp1,
    float* __restrict__ hid, int G_){
  const int lane = threadIdx.x & 63;
  const int row = blockIdx.x*4 + (threadIdx.x >> 6);
  if (row >= G_) return;
  const int c = lane*2;
  float ra0 = hsum[(size_t)row*HID + lane];
  float ra1 = hsum[(size_t)row*HID + 64 + lane];
  float ra2 = hmaxf[(size_t)row*HID + lane];
  float ra3 = hmaxf[(size_t)row*HID + 64 + lane];
  float a0 = 0.f, a1 = 0.f;
  #pragma unroll 4
  for (int k = 0; k < 64; ++k){
    const float v0 = rdl(ra0,k), v1 = rdl(ra1,k), v2 = rdl(ra2,k), v3 = rdl(ra3,k);
    const float2 w0 = *(const float2*)&Wp1[(size_t)(k      )*HID + c];
    const float2 w1 = *(const float2*)&Wp1[(size_t)(k +  64)*HID + c];
    const float2 w2 = *(const float2*)&Wp1[(size_t)(k + 128)*HID + c];
    const float2 w3 = *(const float2*)&Wp1[(size_t)(k + 192)*HID + c];
    a0 = fmaf(v0,w0.x, fmaf(v1,w1.x, fmaf(v2,w2.x, fmaf(v3,w3.x, a0))));
    a1 = fmaf(v0,w0.y, fmaf(v1,w1.y, fmaf(v2,w2.y, fmaf(v3,w3.y, a1))));
  }
  hid[(size_t)row*HID + c]   = fmaxf(a0 + bp1[c],   0.f);
  hid[(size_t)row*HID + c+1] = fmaxf(a1 + bp1[c+1], 0.f);
}

// ---------------- MLP layer 2 + zero-row insertion ----------------
__global__ __launch_bounds__(256) void k_mlp2(
    const float* __restrict__ hid, const float* __restrict__ Wp2,
    const float* __restrict__ bp2, const int* __restrict__ idxw, int K_,
    float* __restrict__ out, int G_){
  const int lane = threadIdx.x & 63;
  const int row = blockIdx.x*4 + (threadIdx.x >> 6);
  if (row >= G_) return;
  const int c = lane*4;
  float ra0 = hid[(size_t)row*HID + lane];
  float ra1 = hid[(size_t)row*HID + 64 + lane];
  float acc0=0.f, acc1=0.f, acc2=0.f, acc3=0.f;
  #pragma unroll 4
  for (int k = 0; k < 64; ++k){
    const float a = rdl(ra0, k);
    const float4 w = *(const float4*)&Wp2[(size_t)k*DIM + c];
    acc0 = fmaf(a,w.x,acc0); acc1 = fmaf(a,w.y,acc1);
    acc2 = fmaf(a,w.z,acc2); acc3 = fmaf(a,w.w,acc3);
  }
  #pragma unroll 4
  for (int k = 64; k < 128; ++k){
    const float a = rdl(ra1, k-64);
    const float4 w = *(const float4*)&Wp2[(size_t)k*DIM + c];
    acc0 = fmaf(a,w.x,acc0); acc1 = fmaf(a,w.y,acc1);
    acc2 = fmaf(a,w.z,acc2); acc3 = fmaf(a,w.w,acc3);
  }
  int orow = row;
  for (int j = 0; j < K_; ++j){ if (idxw[j] <= orow) orow++; }
  float* po = out + (size_t)orow*DIM + c;
  po[0] = acc0 + bp2[c];
  po[1] = acc1 + bp2[c+1];
  po[2] = acc2 + bp2[c+2];
  po[3] = acc3 + bp2[c+3];
}

extern "C" void kernel_launch(void* const* d_in, const int* in_sizes, int n_in,
                              void* d_out, int out_size, void* d_ws, size_t ws_size,
                              hipStream_t stream){
  (void)n_in; (void)ws_size;
  const float* x0     = (const float*)d_in[0];
  // d_in[1] = edge_feats (unused by the reference GCN)
  const float* W1     = (const float*)d_in[2];
  const float* b1     = (const float*)d_in[3];
  const float* Wr1    = (const float*)d_in[4];
  const float* br1    = (const float*)d_in[5];
  const float* W2     = (const float*)d_in[6];
  const float* b2     = (const float*)d_in[7];
  const float* Wr2    = (const float*)d_in[8];
  const float* br2    = (const float*)d_in[9];
  const float* w_atom = (const float*)d_in[10];
  const float* b_atom = (const float*)d_in[11];
  const float* Wp1    = (const float*)d_in[12];
  const float* bp1    = (const float*)d_in[13];
  const float* Wp2    = (const float*)d_in[14];
  const float* bp2    = (const float*)d_in[15];
  const int* src  = (const int*)d_in[16];
  const int* dst  = (const int*)d_in[17];
  const int* gid  = (const int*)d_in[18];
  const int* idxw = (const int*)d_in[19];

  const int N_ = in_sizes[0] / NODE_F;
  const int E_ = in_sizes[16];
  const int K_ = in_sizes[19];
  const int G_ = out_size / DIM - K_;

  // workspace (~33 MB):
  //   [h1u N*64 u32][norm_s N][norm_d N][hsum G*128][hmax G*128][hid G*128]
  //   [indeg/cursor N][row_ptr N+1][col E]
  u32*   h1u     = (u32*)d_ws;
  float* norm_s  = (float*)(h1u + (size_t)N_*(HID/2));
  float* norm_d  = norm_s + N_;
  float* hsum    = norm_d + N_;
  float* hmax    = hsum + (size_t)G_*HID;
  float* hid     = hmax + (size_t)G_*HID;
  int*   indeg   = (int*)(hid + (size_t)G_*HID);
  int*   row_ptr = indeg + N_;
  int*   col     = row_ptr + N_ + 1;

  hipMemsetAsync(norm_s, 0, ((size_t)2*N_ + (size_t)2*G_*HID)*sizeof(float), stream);
  hipMemsetAsync(indeg, 0, (size_t)N_*sizeof(int), stream);
  hipMemsetAsync(d_out, 0, (size_t)out_size*sizeof(float), stream);

  k_deg <<<(E_+255)/256, 256, 0, stream>>>(src, dst, norm_s, indeg, E_);
  k_norm<<<(N_+255)/256, 256, 0, stream>>>(norm_s, indeg, norm_d, N_);
  k_scan<<<1, 1024, 0, stream>>>(indeg, row_ptr, N_);
  k_fill<<<(E_+255)/256, 256, 0, stream>>>(src, dst, row_ptr, indeg, col, E_);

  k_layer1<<<1024, 256, 0, stream>>>(x0, row_ptr, col, norm_s, norm_d,
                                     W1, b1, Wr1, br1, h1u, N_);
  k_layer2<<<1024, 256, 0, stream>>>(h1u, row_ptr, col, norm_s, norm_d,
                                     W2, b2, Wr2, br2, w_atom, b_atom, gid,
                                     hsum, (u32*)hmax, N_);

  k_mlp1<<<(G_+3)/4, 256, 0, stream>>>(hsum, hmax, Wp1, bp1, hid, G_);
  k_mlp2<<<(G_+3)/4, 256, 0, stream>>>(hid, Wp2, bp2, idxw, K_, (float*)d_out, G_);
}